// Round 1
// baseline (75.793 us; speedup 1.0000x reference)
//
#include <hip/hip_runtime.h>

// Q_RUNLayer_Hybrid: monarch(blockdiag R -> stride perm -> blockdiag L) + bias
// -> LayerNorm -> h + (h@Wd)@Wu -> sin/cos reupload (3) -> [PROJ,6]@Wp.T+bp
// Fully fused MFMA implementation, split-bf16 (hi/lo) 3-mult for accuracy.

typedef __attribute__((ext_vector_type(8))) short bf16x8;
typedef __attribute__((ext_vector_type(4))) float f32x4;

#define PITCH 1032            // ushorts per row of hi/lo planes (1024 + 8 pad)
#define DPITCH 68             // floats per row of dbuf
#define DHALF (16 * DPITCH)
#define SMEM_BYTES 74880      // 2*16*1032*2 + 2*16*68*4 + 32*4

__device__ __forceinline__ unsigned short f2bf(float f) {
    unsigned u = __float_as_uint(f);
    u = (u + 0x7FFFu + ((u >> 16) & 1u)) >> 16;   // RNE f32 -> bf16
    return (unsigned short)u;
}
__device__ __forceinline__ float bf2f(unsigned short h) {
    return __uint_as_float(((unsigned)h) << 16);
}
__device__ __forceinline__ void split_bf(float f, unsigned short &hi, unsigned short &lo) {
    hi = f2bf(f);
    lo = f2bf(f - bf2f(hi));
}
__device__ __forceinline__ f32x4 MFMA(bf16x8 a, bf16x8 b, f32x4 c) {
    return __builtin_amdgcn_mfma_f32_16x16x32_bf16(a, b, c, 0, 0, 0);
}

// ---------------------------------------------------------------------------
// Pack weights into MFMA B-fragment order (hi/lo bf16), one 64x64 block per wg.
// ws block layout (16KB each): blk 0..15 = R[b], 16..31 = L[c],
// 32..47 = Wd k-block, 48..63 = Wu n-block.
// Frag addressing (ushorts): blk*8192 + ((kk*4+nt)*2+comp)*512 + lane*8
// element v of lane l:  B[kk*32 + (l>>4)*8 + v][nt*16 + (l&15)]
// ---------------------------------------------------------------------------
__global__ __launch_bounds__(256) void pack_weights(
    const float* __restrict__ R, const float* __restrict__ L,
    const float* __restrict__ Wd, const float* __restrict__ Wu,
    unsigned short* __restrict__ wsp)
{
    const int blk = blockIdx.x;
    const int tid = threadIdx.x;
    unsigned short* dst = wsp + (size_t)blk * 8192;
    for (int it = 0; it < 4; ++it) {
        const int slot = tid + it * 256;       // 0..1023
        const int fragidx = slot >> 6;         // 0..15
        const int l = slot & 63;
        const int kk = fragidx >> 3;
        const int nt = (fragidx >> 1) & 3;
        const int comp = fragidx & 1;
        const int g = l >> 4, r16 = l & 15;
        const int j = nt * 16 + r16;
        bf16x8 s;
        #pragma unroll
        for (int v = 0; v < 8; ++v) {
            const int k = kk * 32 + g * 8 + v;
            float w;
            if (blk < 16)      w = R[(size_t)blk * 4096 + k * 64 + j];
            else if (blk < 32) w = L[(size_t)(blk - 16) * 4096 + k * 64 + j];
            else if (blk < 48) w = Wd[(size_t)((blk - 32) * 64 + k) * 64 + j];
            else               w = Wu[(size_t)k * 1024 + (blk - 48) * 64 + j];
            unsigned short hi = f2bf(w);
            unsigned short bits = (comp == 0) ? hi : f2bf(w - bf2f(hi));
            s[v] = (short)bits;
        }
        *(bf16x8*)(dst + fragidx * 512 + l * 8) = s;
    }
}

// ---------------------------------------------------------------------------
// Fused main kernel. 512 threads (8 waves), 16 tokens per workgroup.
// Wave w: group grp = w>>2 (splits b/c/k loops), ntw = w&3 (16-col subtile).
// h tile lives in LDS as hi/lo bf16 planes [16][PITCH].
// ---------------------------------------------------------------------------
__global__ __launch_bounds__(512) void qrun_main(
    const float* __restrict__ x, const float* __restrict__ bias,
    const float* __restrict__ gamma, const float* __restrict__ beta,
    const float* __restrict__ thetas, const float* __restrict__ phis,
    const float* __restrict__ Wp, const float* __restrict__ bpv,
    const unsigned short* __restrict__ wpk, float* __restrict__ out)
{
    extern __shared__ char smem[];
    unsigned short* hiP = (unsigned short*)smem;          // [16][PITCH]
    unsigned short* loP = hiP + 16 * PITCH;               // [16][PITCH]
    float* dbuf = (float*)(loP + 16 * PITCH);             // [2][16][DPITCH]
    float* statsL = dbuf + 2 * DHALF;                     // [16][2]

    const int tid = threadIdx.x;
    const int wave = tid >> 6, lane = tid & 63;
    const int g = lane >> 4, r16 = lane & 15;
    const int grp = wave >> 2, ntw = wave & 3;
    const size_t n0 = (size_t)blockIdx.x * 16;
    const int rowA = r16 * PITCH;                         // A-frag row base (token=r16)

    // ---- phase 0: load x tile, split to hi/lo bf16 planes ----
    {
        const float4* xv = (const float4*)(x + n0 * 1024);
        #pragma unroll 1
        for (int i = tid; i < 4096; i += 512) {
            float4 f = xv[i];
            const int row = i >> 8, col = (i & 255) << 2;
            unsigned short h0,h1,h2,h3,l0,l1,l2,l3;
            split_bf(f.x,h0,l0); split_bf(f.y,h1,l1);
            split_bf(f.z,h2,l2); split_bf(f.w,h3,l3);
            *(ushort4*)(hiP + row * PITCH + col) = make_ushort4(h0,h1,h2,h3);
            *(ushort4*)(loP + row * PITCH + col) = make_ushort4(l0,l1,l2,l3);
        }
    }
    __syncthreads();

    // ---- phase 1: monarch stage 1 (x @ R[b]), in-place per block ----
    #pragma unroll 1
    for (int bi = 0; bi < 8; ++bi) {
        const int b = grp * 8 + bi;
        const unsigned short* wb = wpk + (size_t)b * 8192;
        bf16x8 Bh0 = *(const bf16x8*)(wb + ((0*4+ntw)*2+0)*512 + lane*8);
        bf16x8 Bl0 = *(const bf16x8*)(wb + ((0*4+ntw)*2+1)*512 + lane*8);
        bf16x8 Bh1 = *(const bf16x8*)(wb + ((1*4+ntw)*2+0)*512 + lane*8);
        bf16x8 Bl1 = *(const bf16x8*)(wb + ((1*4+ntw)*2+1)*512 + lane*8);
        const int ca = b * 64 + g * 8;
        bf16x8 Ah0 = *(const bf16x8*)(hiP + rowA + ca);
        bf16x8 Al0 = *(const bf16x8*)(loP + rowA + ca);
        bf16x8 Ah1 = *(const bf16x8*)(hiP + rowA + ca + 32);
        bf16x8 Al1 = *(const bf16x8*)(loP + rowA + ca + 32);
        __syncthreads();   // all reads of x block(s) done before overwrite
        f32x4 acc = {0.f, 0.f, 0.f, 0.f};
        acc = MFMA(Ah0, Bh0, acc); acc = MFMA(Ah0, Bl0, acc); acc = MFMA(Al0, Bh0, acc);
        acc = MFMA(Ah1, Bh1, acc); acc = MFMA(Ah1, Bl1, acc); acc = MFMA(Al1, Bh1, acc);
        const int colD = b * 64 + ntw * 16 + r16;
        #pragma unroll
        for (int v = 0; v < 4; ++v) {
            unsigned short hh, ll;
            split_bf(acc[v], hh, ll);
            const int rowD = (g * 4 + v) * PITCH;
            hiP[rowD + colD] = hh; loP[rowD + colD] = ll;
        }
    }
    __syncthreads();

    // ---- phase 2: monarch stage 2 (perm gather @ L[c]) + bias ----
    // perm: A element i' = kk*32+g*8+v reads source col
    //       (8*(g&1)+v)*64 + c*4 + kk*2 + (g>>1)
    f32x4 acc2[8];
    {
        const int cbase = rowA + 512 * (g & 1) + (g >> 1);
        #pragma unroll
        for (int ci = 0; ci < 8; ++ci) {
            const int c = grp * 8 + ci;
            const unsigned short* wb = wpk + (size_t)(16 + c) * 8192;
            bf16x8 Bh0 = *(const bf16x8*)(wb + ((0*4+ntw)*2+0)*512 + lane*8);
            bf16x8 Bl0 = *(const bf16x8*)(wb + ((0*4+ntw)*2+1)*512 + lane*8);
            bf16x8 Bh1 = *(const bf16x8*)(wb + ((1*4+ntw)*2+0)*512 + lane*8);
            bf16x8 Bl1 = *(const bf16x8*)(wb + ((1*4+ntw)*2+1)*512 + lane*8);
            bf16x8 Ah0, Al0, Ah1, Al1;
            #pragma unroll
            for (int v = 0; v < 8; ++v) {
                const int o0 = cbase + c * 4 + v * 64;       // kk = 0
                const int o1 = o0 + 2;                       // kk = 1
                Ah0[v] = (short)hiP[o0]; Al0[v] = (short)loP[o0];
                Ah1[v] = (short)hiP[o1]; Al1[v] = (short)loP[o1];
            }
            f32x4 a = {0.f, 0.f, 0.f, 0.f};
            a = MFMA(Ah0, Bh0, a); a = MFMA(Ah0, Bl0, a); a = MFMA(Al0, Bh0, a);
            a = MFMA(Ah1, Bh1, a); a = MFMA(Ah1, Bl1, a); a = MFMA(Al1, Bh1, a);
            acc2[ci] = a;
        }
    }
    __syncthreads();     // all gather reads complete before overwrite
    #pragma unroll
    for (int ci = 0; ci < 8; ++ci) {
        const int c = grp * 8 + ci;
        const int colD = c * 64 + ntw * 16 + r16;
        const float bv = bias[colD];
        #pragma unroll
        for (int v = 0; v < 4; ++v) {
            unsigned short hh, ll;
            split_bf(acc2[ci][v] + bv, hh, ll);
            const int rowD = (g * 4 + v) * PITCH;
            hiP[rowD + colD] = hh; loP[rowD + colD] = ll;
        }
    }
    __syncthreads();

    // ---- phase 3: LayerNorm stats (2 rows per wave) ----
    #pragma unroll
    for (int rr = 0; rr < 2; ++rr) {
        const int row = wave * 2 + rr;
        const unsigned short* hp = hiP + row * PITCH + lane * 16;
        const unsigned short* lp = loP + row * PITCH + lane * 16;
        bf16x8 a0 = *(const bf16x8*)hp, a1 = *(const bf16x8*)(hp + 8);
        bf16x8 b0 = *(const bf16x8*)lp, b1 = *(const bf16x8*)(lp + 8);
        float s = 0.f, s2 = 0.f;
        #pragma unroll
        for (int v = 0; v < 8; ++v) {
            float f0 = bf2f((unsigned short)a0[v]) + bf2f((unsigned short)b0[v]);
            float f1 = bf2f((unsigned short)a1[v]) + bf2f((unsigned short)b1[v]);
            s += f0 + f1; s2 += f0 * f0 + f1 * f1;
        }
        #pragma unroll
        for (int m = 1; m < 64; m <<= 1) {
            s += __shfl_xor(s, m); s2 += __shfl_xor(s2, m);
        }
        if (lane == 0) {
            const float mu = s * (1.f / 1024.f);
            const float var = s2 * (1.f / 1024.f) - mu * mu;
            statsL[row * 2] = mu;
            statsL[row * 2 + 1] = rsqrtf(var + 1e-5f);
        }
    }
    __syncthreads();

    // ---- phase 3.5: normalize in place (affine with gamma/beta) ----
    #pragma unroll 1
    for (int i = tid; i < 4096; i += 512) {
        const int row = i >> 8, col = (i & 255) << 2;
        ushort4 h4 = *(ushort4*)(hiP + row * PITCH + col);
        ushort4 l4 = *(ushort4*)(loP + row * PITCH + col);
        const float mu = statsL[row * 2], rs = statsL[row * 2 + 1];
        const float4 gm = *(const float4*)(gamma + col);
        const float4 bt = *(const float4*)(beta + col);
        float f0 = (bf2f(h4.x) + bf2f(l4.x) - mu) * rs * gm.x + bt.x;
        float f1 = (bf2f(h4.y) + bf2f(l4.y) - mu) * rs * gm.y + bt.y;
        float f2 = (bf2f(h4.z) + bf2f(l4.z) - mu) * rs * gm.z + bt.z;
        float f3 = (bf2f(h4.w) + bf2f(l4.w) - mu) * rs * gm.w + bt.w;
        split_bf(f0, h4.x, l4.x); split_bf(f1, h4.y, l4.y);
        split_bf(f2, h4.z, l4.z); split_bf(f3, h4.w, l4.w);
        *(ushort4*)(hiP + row * PITCH + col) = h4;
        *(ushort4*)(loP + row * PITCH + col) = l4;
    }
    __syncthreads();

    // ---- phase 4: down-proj d = hn @ Wd (K split across wave groups) ----
    {
        f32x4 accd = {0.f, 0.f, 0.f, 0.f};
        #pragma unroll
        for (int ki = 0; ki < 16; ++ki) {
            const int kkg = grp * 16 + ki;
            const int kb = kkg >> 1, kin = kkg & 1;
            const unsigned short* wb = wpk + (size_t)(32 + kb) * 8192;
            bf16x8 Bh = *(const bf16x8*)(wb + ((kin*4+ntw)*2+0)*512 + lane*8);
            bf16x8 Bl = *(const bf16x8*)(wb + ((kin*4+ntw)*2+1)*512 + lane*8);
            const int ca = kkg * 32 + g * 8;
            bf16x8 Ah = *(const bf16x8*)(hiP + rowA + ca);
            bf16x8 Al = *(const bf16x8*)(loP + rowA + ca);
            accd = MFMA(Ah, Bh, accd);
            accd = MFMA(Ah, Bl, accd);
            accd = MFMA(Al, Bh, accd);
        }
        #pragma unroll
        for (int v = 0; v < 4; ++v)
            dbuf[grp * DHALF + (g * 4 + v) * DPITCH + ntw * 16 + r16] = accd[v];
    }
    __syncthreads();

    // ---- phase 5: up-proj + residual + sin/cos reupload + final linear ----
    bf16x8 dAh[2], dAl[2];
    #pragma unroll
    for (int kk = 0; kk < 2; ++kk) {
        #pragma unroll
        for (int v = 0; v < 8; ++v) {
            const int idx = r16 * DPITCH + kk * 32 + g * 8 + v;
            const float f = dbuf[idx] + dbuf[DHALF + idx];   // sum K-halves
            unsigned short hh, ll;
            split_bf(f, hh, ll);
            dAh[kk][v] = (short)hh; dAl[kk][v] = (short)ll;
        }
    }
    float wp[24];
    #pragma unroll
    for (int k2 = 0; k2 < 24; ++k2) wp[k2] = Wp[k2];
    const float bp0 = bpv[0], bp1 = bpv[1], bp2 = bpv[2], bp3 = bpv[3];

    #pragma unroll 1
    for (int j = 0; j < 8; ++j) {
        const int ntg = wave * 8 + j;
        const int nb = ntg >> 2, ntin = ntg & 3;
        const unsigned short* wb = wpk + (size_t)(48 + nb) * 8192;
        bf16x8 Bh0 = *(const bf16x8*)(wb + ((0*4+ntin)*2+0)*512 + lane*8);
        bf16x8 Bl0 = *(const bf16x8*)(wb + ((0*4+ntin)*2+1)*512 + lane*8);
        bf16x8 Bh1 = *(const bf16x8*)(wb + ((1*4+ntin)*2+0)*512 + lane*8);
        bf16x8 Bl1 = *(const bf16x8*)(wb + ((1*4+ntin)*2+1)*512 + lane*8);
        f32x4 au = {0.f, 0.f, 0.f, 0.f};
        au = MFMA(dAh[0], Bh0, au); au = MFMA(dAh[0], Bl0, au); au = MFMA(dAl[0], Bh0, au);
        au = MFMA(dAh[1], Bh1, au); au = MFMA(dAh[1], Bl1, au); au = MFMA(dAl[1], Bh1, au);
        const int p = ntg * 16 + r16;
        const float th0 = thetas[p], th1 = thetas[1024 + p], th2 = thetas[2048 + p];
        const float ph0 = phis[p],   ph1 = phis[1024 + p],   ph2 = phis[2048 + p];
        #pragma unroll
        for (int v = 0; v < 4; ++v) {
            const int row = g * 4 + v;
            const float hn = bf2f(hiP[row * PITCH + p]) + bf2f(loP[row * PITCH + p]);
            const float e = au[v] + hn;
            float o0 = bp0, o1 = bp1, o2 = bp2, o3 = bp3;
            {
                const float rot = fmaf(e, th0, ph0);
                const float sn = __sinf(rot), cs = __cosf(rot);
                o0 = fmaf(sn, wp[0],  fmaf(cs, wp[1],  o0));
                o1 = fmaf(sn, wp[6],  fmaf(cs, wp[7],  o1));
                o2 = fmaf(sn, wp[12], fmaf(cs, wp[13], o2));
                o3 = fmaf(sn, wp[18], fmaf(cs, wp[19], o3));
            }
            {
                const float rot = fmaf(e, th1, ph1);
                const float sn = __sinf(rot), cs = __cosf(rot);
                o0 = fmaf(sn, wp[2],  fmaf(cs, wp[3],  o0));
                o1 = fmaf(sn, wp[8],  fmaf(cs, wp[9],  o1));
                o2 = fmaf(sn, wp[14], fmaf(cs, wp[15], o2));
                o3 = fmaf(sn, wp[20], fmaf(cs, wp[21], o3));
            }
            {
                const float rot = fmaf(e, th2, ph2);
                const float sn = __sinf(rot), cs = __cosf(rot);
                o0 = fmaf(sn, wp[4],  fmaf(cs, wp[5],  o0));
                o1 = fmaf(sn, wp[10], fmaf(cs, wp[11], o1));
                o2 = fmaf(sn, wp[16], fmaf(cs, wp[17], o2));
                o3 = fmaf(sn, wp[22], fmaf(cs, wp[23], o3));
            }
            *(float4*)(out + ((n0 + row) * 1024 + p) * 4) = make_float4(o0, o1, o2, o3);
        }
    }
}

extern "C" void kernel_launch(void* const* d_in, const int* in_sizes, int n_in,
                              void* d_out, int out_size, void* d_ws, size_t ws_size,
                              hipStream_t stream) {
    const float* x      = (const float*)d_in[0];
    const float* R      = (const float*)d_in[1];
    const float* L      = (const float*)d_in[2];
    const float* bias   = (const float*)d_in[3];
    const float* gamma  = (const float*)d_in[4];
    const float* beta   = (const float*)d_in[5];
    const float* Wd     = (const float*)d_in[6];
    const float* Wu     = (const float*)d_in[7];
    const float* thetas = (const float*)d_in[8];
    const float* phis   = (const float*)d_in[9];
    const float* Wp     = (const float*)d_in[10];
    const float* bp     = (const float*)d_in[11];
    float* out = (float*)d_out;
    unsigned short* wsp = (unsigned short*)d_ws;
    const int N = in_sizes[0] / 1024;   // 8192 tokens

    (void)hipFuncSetAttribute((const void*)qrun_main,
                              hipFuncAttributeMaxDynamicSharedMemorySize, SMEM_BYTES);
    pack_weights<<<dim3(64), dim3(256), 0, stream>>>(R, L, Wd, Wu, wsp);
    qrun_main<<<dim3(N / 16), dim3(512), SMEM_BYTES, stream>>>(
        x, bias, gamma, beta, thetas, phis, Wp, bp, wsp, out);
}

// Round 2
// 68.171 us; speedup vs baseline: 1.1118x; 1.1118x over previous
//
#include <hip/hip_runtime.h>

// Q_RUNLayer_Hybrid: monarch(blockdiag R -> stride perm -> blockdiag L) + bias
// -> LayerNorm -> h + (h@Wd)@Wu -> sin/cos reupload (3) -> [PROJ,6]@Wp.T+bp
// Fused MFMA implementation. Split-bf16 (hi/lo) for monarch + stored h;
// hi-only bf16 for down/up projection. Permutation folded into stage-1
// writes (XOR-swizzled), stage-2/down-proj operand-swapped for vector writes.

typedef __attribute__((ext_vector_type(8))) short bf16x8;
typedef __attribute__((ext_vector_type(4))) float f32x4;

#define PITCH 1032            // ushorts per plane row (1024 + 8 pad, 16B-aligned rows)
#define DPITCH 68             // floats per dbuf row
#define DHALF (16 * DPITCH)   // 1088
#define SMEM_BYTES 75776      // 2*16*1032*2 + 2*1088*4 + 8*16*2*4

__device__ __forceinline__ unsigned short f2bf(float f) {
    unsigned u = __float_as_uint(f);
    u = (u + 0x7FFFu + ((u >> 16) & 1u)) >> 16;   // RNE f32 -> bf16
    return (unsigned short)u;
}
__device__ __forceinline__ float bf2f(unsigned short h) {
    return __uint_as_float(((unsigned)h) << 16);
}
__device__ __forceinline__ void split_bf(float f, unsigned short &hi, unsigned short &lo) {
    hi = f2bf(f);
    lo = f2bf(f - bf2f(hi));
}
__device__ __forceinline__ f32x4 MFMA(bf16x8 a, bf16x8 b, f32x4 c) {
    return __builtin_amdgcn_mfma_f32_16x16x32_bf16(a, b, c, 0, 0, 0);
}

// ---------------------------------------------------------------------------
// Pack weights into MFMA fragment order (hi/lo bf16), one 64x64 block per wg.
// blk 0..15 = R[b], 16..31 = L[c], 32..47 = Wd k-block, 48..63 = Wu n-block.
// Frag addressing (ushorts): blk*8192 + ((kk*4+nt)*2+comp)*512 + lane*8
// element v of lane l:  M[kk*32 + (l>>4)*8 + v][nt*16 + (l&15)]
// (A-frag of M^T == B-frag of M, so the same bytes serve both operand sides.)
// ---------------------------------------------------------------------------
__global__ __launch_bounds__(256) void pack_weights(
    const float* __restrict__ R, const float* __restrict__ L,
    const float* __restrict__ Wd, const float* __restrict__ Wu,
    unsigned short* __restrict__ wsp)
{
    const int blk = blockIdx.x;
    const int tid = threadIdx.x;
    unsigned short* dst = wsp + (size_t)blk * 8192;
    for (int it = 0; it < 4; ++it) {
        const int slot = tid + it * 256;       // 0..1023
        const int fragidx = slot >> 6;         // 0..15
        const int l = slot & 63;
        const int kk = fragidx >> 3;
        const int nt = (fragidx >> 1) & 3;
        const int comp = fragidx & 1;
        const int g = l >> 4, r16 = l & 15;
        const int j = nt * 16 + r16;
        bf16x8 s;
        #pragma unroll
        for (int v = 0; v < 8; ++v) {
            const int k = kk * 32 + g * 8 + v;
            float w;
            if (blk < 16)      w = R[(size_t)blk * 4096 + k * 64 + j];
            else if (blk < 32) w = L[(size_t)(blk - 16) * 4096 + k * 64 + j];
            else if (blk < 48) w = Wd[(size_t)((blk - 32) * 64 + k) * 64 + j];
            else               w = Wu[(size_t)k * 1024 + (blk - 48) * 64 + j];
            unsigned short hi = f2bf(w);
            unsigned short bits = (comp == 0) ? hi : f2bf(w - bf2f(hi));
            s[v] = (short)bits;
        }
        *(bf16x8*)(dst + fragidx * 512 + l * 8) = s;
    }
}

// ---------------------------------------------------------------------------
// Fused main kernel. 512 threads (8 waves), 16 tokens per workgroup.
// Wave w: grp = w>>2 (splits block/K loops), ntw = w&3 (16-col subtile).
// ---------------------------------------------------------------------------
__global__ __launch_bounds__(512, 4) void qrun_main(
    const float* __restrict__ x, const float* __restrict__ bias,
    const float* __restrict__ gamma, const float* __restrict__ beta,
    const float* __restrict__ thetas, const float* __restrict__ phis,
    const float* __restrict__ Wp, const float* __restrict__ bpv,
    const unsigned short* __restrict__ wpk, float* __restrict__ out)
{
    extern __shared__ char smem[];
    unsigned short* hiP = (unsigned short*)smem;          // [16][PITCH]
    unsigned short* loP = hiP + 16 * PITCH;               // [16][PITCH]
    float* dbuf = (float*)(loP + 16 * PITCH);             // [2][16][DPITCH]
    float* lnpart = dbuf + 2 * DHALF;                     // [8][16][2]

    const int tid = threadIdx.x;
    const int wave = tid >> 6, lane = tid & 63;
    const int g = lane >> 4, r16 = lane & 15;
    const int grp = wave >> 2, ntw = wave & 3;
    const size_t n0 = (size_t)blockIdx.x * 16;
    const int rowA = r16 * PITCH;

    // ---- phase 0: load x tile, split to hi/lo bf16 planes ----
    {
        #pragma unroll
        for (int it = 0; it < 4; ++it) {
            const int base = (it * 512 + tid) * 8;        // flat element index
            const int row = base >> 10, col = base & 1023;
            const float4 f0 = *(const float4*)(x + n0 * 1024 + base);
            const float4 f1 = *(const float4*)(x + n0 * 1024 + base + 4);
            bf16x8 hv, lv;
            unsigned short hh, ll;
            split_bf(f0.x, hh, ll); hv[0] = (short)hh; lv[0] = (short)ll;
            split_bf(f0.y, hh, ll); hv[1] = (short)hh; lv[1] = (short)ll;
            split_bf(f0.z, hh, ll); hv[2] = (short)hh; lv[2] = (short)ll;
            split_bf(f0.w, hh, ll); hv[3] = (short)hh; lv[3] = (short)ll;
            split_bf(f1.x, hh, ll); hv[4] = (short)hh; lv[4] = (short)ll;
            split_bf(f1.y, hh, ll); hv[5] = (short)hh; lv[5] = (short)ll;
            split_bf(f1.z, hh, ll); hv[6] = (short)hh; lv[6] = (short)ll;
            split_bf(f1.w, hh, ll); hv[7] = (short)hh; lv[7] = (short)ll;
            *(bf16x8*)(hiP + row * PITCH + col) = hv;
            *(bf16x8*)(loP + row * PITCH + col) = lv;
        }
    }
    __syncthreads();

    // ---- phase 1: monarch stage 1 (x @ R[b]); reads all -> barrier -> writes ----
    f32x4 acc1[8];
    #pragma unroll
    for (int bi = 0; bi < 8; ++bi) {
        const int b = grp * 8 + bi;
        const unsigned short* wb = wpk + (size_t)b * 8192;
        bf16x8 Bh0 = *(const bf16x8*)(wb + ((0*4+ntw)*2+0)*512 + lane*8);
        bf16x8 Bl0 = *(const bf16x8*)(wb + ((0*4+ntw)*2+1)*512 + lane*8);
        bf16x8 Bh1 = *(const bf16x8*)(wb + ((1*4+ntw)*2+0)*512 + lane*8);
        bf16x8 Bl1 = *(const bf16x8*)(wb + ((1*4+ntw)*2+1)*512 + lane*8);
        const int ca = b * 64 + g * 8;
        bf16x8 Ah0 = *(const bf16x8*)(hiP + rowA + ca);
        bf16x8 Al0 = *(const bf16x8*)(loP + rowA + ca);
        bf16x8 Ah1 = *(const bf16x8*)(hiP + rowA + ca + 32);
        bf16x8 Al1 = *(const bf16x8*)(loP + rowA + ca + 32);
        f32x4 a = {0.f, 0.f, 0.f, 0.f};
        a = MFMA(Ah0, Bh0, a); a = MFMA(Ah0, Bl0, a); a = MFMA(Al0, Bh0, a);
        a = MFMA(Ah1, Bh1, a); a = MFMA(Ah1, Bl1, a); a = MFMA(Al1, Bh1, a);
        acc1[bi] = a;
    }
    __syncthreads();   // all stage-1 reads complete before permuted overwrite

    // permuted write: value at (row, colD=b*64+ntw*16+r16) -> col
    //   c'=ntw*4+(r16>>2), kk'=(r16>>1)&1, g'=(grp+2*(r16&1)) ^ (r16>>2)  [XOR swizzle]
    //   v'=b&7  -> the 8 blocks are 8 consecutive columns => b128 write.
    {
        const int Cw = (ntw * 4 + (r16 >> 2)) * 64 + ((r16 >> 1) & 1) * 32
                     + (((grp + 2 * (r16 & 1)) ^ (r16 >> 2)) << 3);
        #pragma unroll
        for (int v = 0; v < 4; ++v) {
            const int rowv = (g * 4 + v) * PITCH;
            bf16x8 hv, lv;
            #pragma unroll
            for (int bi = 0; bi < 8; ++bi) {
                unsigned short hh, ll;
                split_bf(acc1[bi][v], hh, ll);
                hv[bi] = (short)hh; lv[bi] = (short)ll;
            }
            *(bf16x8*)(hiP + rowv + Cw) = hv;
            *(bf16x8*)(loP + rowv + Cw) = lv;
        }
    }
    __syncthreads();

    // ---- phase 2: monarch stage 2, operand-swapped: h2^T = L^T @ mid^T ----
    // A = L^T (packed bytes identical to B-frag of L), B = permuted h1 tile.
    f32x4 acc2[8];
    #pragma unroll
    for (int ci = 0; ci < 8; ++ci) {
        const int c = grp * 8 + ci;
        const unsigned short* wb = wpk + (size_t)(16 + c) * 8192;
        bf16x8 Wh0 = *(const bf16x8*)(wb + ((0*4+ntw)*2+0)*512 + lane*8);
        bf16x8 Wl0 = *(const bf16x8*)(wb + ((0*4+ntw)*2+1)*512 + lane*8);
        bf16x8 Wh1 = *(const bf16x8*)(wb + ((1*4+ntw)*2+0)*512 + lane*8);
        bf16x8 Wl1 = *(const bf16x8*)(wb + ((1*4+ntw)*2+1)*512 + lane*8);
        const int gx = ((g ^ (c & 3)) << 3);               // XOR swizzle (read side)
        const int c0 = rowA + c * 64 + gx;                 // kk=0
        const int c1 = c0 + 32;                            // kk=1
        bf16x8 Hh0 = *(const bf16x8*)(hiP + c0);
        bf16x8 Hl0 = *(const bf16x8*)(loP + c0);
        bf16x8 Hh1 = *(const bf16x8*)(hiP + c1);
        bf16x8 Hl1 = *(const bf16x8*)(loP + c1);
        f32x4 a = {0.f, 0.f, 0.f, 0.f};
        a = MFMA(Wh0, Hh0, a); a = MFMA(Wh0, Hl0, a); a = MFMA(Wl0, Hh0, a);
        a = MFMA(Wh1, Hh1, a); a = MFMA(Wh1, Hl1, a); a = MFMA(Wl1, Hh1, a);
        acc2[ci] = a;
    }
    __syncthreads();   // all permuted-tile reads complete before overwrite

    // epilogue: +bias, write h2 (standard [token][n], token = r16), LN partials
    {
        float s = 0.f, s2 = 0.f;
        #pragma unroll
        for (int ci = 0; ci < 8; ++ci) {
            const int c = grp * 8 + ci;
            const int ncol = c * 64 + ntw * 16 + g * 4;
            const float4 bv = *(const float4*)(bias + ncol);
            float f0 = acc2[ci][0] + bv.x, f1 = acc2[ci][1] + bv.y;
            float f2 = acc2[ci][2] + bv.z, f3 = acc2[ci][3] + bv.w;
            s += f0 + f1 + f2 + f3;
            s2 += f0*f0 + f1*f1 + f2*f2 + f3*f3;
            ushort4 h4, l4;
            split_bf(f0, h4.x, l4.x); split_bf(f1, h4.y, l4.y);
            split_bf(f2, h4.z, l4.z); split_bf(f3, h4.w, l4.w);
            *(ushort4*)(hiP + rowA + ncol) = h4;
            *(ushort4*)(loP + rowA + ncol) = l4;
        }
        // token = r16: reduce over g (lanes r16, r16+16, r16+32, r16+48)
        s  += __shfl_xor(s, 16);  s  += __shfl_xor(s, 32);
        s2 += __shfl_xor(s2, 16); s2 += __shfl_xor(s2, 32);
        if (g == 0) {
            lnpart[(wave * 16 + r16) * 2]     = s;
            lnpart[(wave * 16 + r16) * 2 + 1] = s2;
        }
    }
    __syncthreads();

    // ---- phase 3: normalize in place; each thread owns 32 elems of one row ----
    {
        const int row = tid >> 5;
        float sm = 0.f, sq = 0.f;
        #pragma unroll
        for (int w = 0; w < 8; ++w) {
            sm += lnpart[(w * 16 + row) * 2];
            sq += lnpart[(w * 16 + row) * 2 + 1];
        }
        const float mu = sm * (1.f / 1024.f);
        const float rs = rsqrtf(sq * (1.f / 1024.f) - mu * mu + 1e-5f);
        const int cb = (tid & 31) * 32;
        #pragma unroll
        for (int it = 0; it < 4; ++it) {
            const int col = cb + it * 8;
            bf16x8 hv = *(bf16x8*)(hiP + row * PITCH + col);
            bf16x8 lv = *(bf16x8*)(loP + row * PITCH + col);
            const float4 gm0 = *(const float4*)(gamma + col);
            const float4 gm1 = *(const float4*)(gamma + col + 4);
            const float4 bt0 = *(const float4*)(beta + col);
            const float4 bt1 = *(const float4*)(beta + col + 4);
            const float gm[8] = {gm0.x,gm0.y,gm0.z,gm0.w,gm1.x,gm1.y,gm1.z,gm1.w};
            const float bt[8] = {bt0.x,bt0.y,bt0.z,bt0.w,bt1.x,bt1.y,bt1.z,bt1.w};
            #pragma unroll
            for (int v = 0; v < 8; ++v) {
                float f = bf2f((unsigned short)hv[v]) + bf2f((unsigned short)lv[v]);
                f = (f - mu) * rs * gm[v] + bt[v];
                unsigned short hh, ll;
                split_bf(f, hh, ll);
                hv[v] = (short)hh; lv[v] = (short)ll;
            }
            *(bf16x8*)(hiP + row * PITCH + col) = hv;
            *(bf16x8*)(loP + row * PITCH + col) = lv;
        }
    }
    __syncthreads();

    // ---- phase 4: down-proj, swapped: d^T = Wd^T @ hn^T (hi-only bf16) ----
    {
        f32x4 accd = {0.f, 0.f, 0.f, 0.f};
        #pragma unroll
        for (int ki = 0; ki < 16; ++ki) {
            const int kq = grp * 16 + ki;                 // 32-wide K chunk (of 32)
            const int kb = kq >> 1, kin = kq & 1;
            const unsigned short* wb = wpk + (size_t)(32 + kb) * 8192;
            bf16x8 Wh = *(const bf16x8*)(wb + ((kin*4+ntw)*2+0)*512 + lane*8);
            bf16x8 Hh = *(const bf16x8*)(hiP + rowA + kq * 32 + g * 8);
            accd = MFMA(Wh, Hh, accd);
        }
        // D[row = rank-local g*4+v][col = token r16]; rank r = ntw*16 + g*4 + v
        *(f32x4*)(dbuf + grp * DHALF + r16 * DPITCH + ntw * 16 + g * 4) = accd;
    }
    __syncthreads();

    // ---- phase 5: up-proj + residual + sin/cos reupload + final linear ----
    bf16x8 dA[2];
    #pragma unroll
    for (int kk = 0; kk < 2; ++kk) {
        const int di = r16 * DPITCH + kk * 32 + g * 8;
        const f32x4 q0 = *(const f32x4*)(dbuf + di);
        const f32x4 q1 = *(const f32x4*)(dbuf + di + 4);
        const f32x4 p0 = *(const f32x4*)(dbuf + DHALF + di);
        const f32x4 p1 = *(const f32x4*)(dbuf + DHALF + di + 4);
        #pragma unroll
        for (int v = 0; v < 4; ++v) {
            dA[kk][v]     = (short)f2bf(q0[v] + p0[v]);
            dA[kk][v + 4] = (short)f2bf(q1[v] + p1[v]);
        }
    }
    float wp[24];
    #pragma unroll
    for (int k2 = 0; k2 < 24; ++k2) wp[k2] = Wp[k2];
    const float bp0 = bpv[0], bp1 = bpv[1], bp2 = bpv[2], bp3 = bpv[3];

    #pragma unroll 1
    for (int j = 0; j < 8; ++j) {
        const int ntg = wave * 8 + j;
        const int nb = ntg >> 2, ntin = ntg & 3;
        const unsigned short* wb = wpk + (size_t)(48 + nb) * 8192;
        bf16x8 Bh0 = *(const bf16x8*)(wb + ((0*4+ntin)*2+0)*512 + lane*8);
        bf16x8 Bh1 = *(const bf16x8*)(wb + ((1*4+ntin)*2+0)*512 + lane*8);
        f32x4 au = {0.f, 0.f, 0.f, 0.f};
        au = MFMA(dA[0], Bh0, au);
        au = MFMA(dA[1], Bh1, au);
        const int p = ntg * 16 + r16;
        const float th0 = thetas[p], th1 = thetas[1024 + p], th2 = thetas[2048 + p];
        const float ph0 = phis[p],   ph1 = phis[1024 + p],   ph2 = phis[2048 + p];
        #pragma unroll
        for (int v = 0; v < 4; ++v) {
            const int row = g * 4 + v;
            const float hn = bf2f(hiP[row * PITCH + p]) + bf2f(loP[row * PITCH + p]);
            const float e = au[v] + hn;
            float o0 = bp0, o1 = bp1, o2 = bp2, o3 = bp3;
            {
                const float rot = fmaf(e, th0, ph0);
                const float sn = __sinf(rot), cs = __cosf(rot);
                o0 = fmaf(sn, wp[0],  fmaf(cs, wp[1],  o0));
                o1 = fmaf(sn, wp[6],  fmaf(cs, wp[7],  o1));
                o2 = fmaf(sn, wp[12], fmaf(cs, wp[13], o2));
                o3 = fmaf(sn, wp[18], fmaf(cs, wp[19], o3));
            }
            {
                const float rot = fmaf(e, th1, ph1);
                const float sn = __sinf(rot), cs = __cosf(rot);
                o0 = fmaf(sn, wp[2],  fmaf(cs, wp[3],  o0));
                o1 = fmaf(sn, wp[8],  fmaf(cs, wp[9],  o1));
                o2 = fmaf(sn, wp[14], fmaf(cs, wp[15], o2));
                o3 = fmaf(sn, wp[20], fmaf(cs, wp[21], o3));
            }
            {
                const float rot = fmaf(e, th2, ph2);
                const float sn = __sinf(rot), cs = __cosf(rot);
                o0 = fmaf(sn, wp[4],  fmaf(cs, wp[5],  o0));
                o1 = fmaf(sn, wp[10], fmaf(cs, wp[11], o1));
                o2 = fmaf(sn, wp[16], fmaf(cs, wp[17], o2));
                o3 = fmaf(sn, wp[22], fmaf(cs, wp[23], o3));
            }
            *(float4*)(out + ((n0 + row) * 1024 + p) * 4) = make_float4(o0, o1, o2, o3);
        }
    }
}

extern "C" void kernel_launch(void* const* d_in, const int* in_sizes, int n_in,
                              void* d_out, int out_size, void* d_ws, size_t ws_size,
                              hipStream_t stream) {
    const float* x      = (const float*)d_in[0];
    const float* R      = (const float*)d_in[1];
    const float* L      = (const float*)d_in[2];
    const float* bias   = (const float*)d_in[3];
    const float* gamma  = (const float*)d_in[4];
    const float* beta   = (const float*)d_in[5];
    const float* Wd     = (const float*)d_in[6];
    const float* Wu     = (const float*)d_in[7];
    const float* thetas = (const float*)d_in[8];
    const float* phis   = (const float*)d_in[9];
    const float* Wp     = (const float*)d_in[10];
    const float* bp     = (const float*)d_in[11];
    float* out = (float*)d_out;
    unsigned short* wsp = (unsigned short*)d_ws;
    const int N = in_sizes[0] / 1024;   // 8192 tokens

    (void)hipFuncSetAttribute((const void*)qrun_main,
                              hipFuncAttributeMaxDynamicSharedMemorySize, SMEM_BYTES);
    pack_weights<<<dim3(64), dim3(256), 0, stream>>>(R, L, Wd, Wu, wsp);
    qrun_main<<<dim3(N / 16), dim3(512), SMEM_BYTES, stream>>>(
        x, bias, gamma, beta, thetas, phis, Wp, bp, wsp, out);
}

// Round 3
// 62.554 us; speedup vs baseline: 1.2116x; 1.0898x over previous
//
#include <hip/hip_runtime.h>

// Q_RUNLayer_Hybrid: monarch(blockdiag R -> stride perm -> blockdiag L) + bias
// -> LayerNorm -> h + (h@Wd)@Wu -> sin/cos reupload (3) -> [PROJ,6]@Wp.T+bp
// Fused MFMA implementation. Split-bf16 (hi/lo) for monarch + stored h.
// LayerNorm is FOLDED: down-proj uses Wd' = diag(gamma)@Wd (packed) plus
// per-token fixup d = rs*(h@Wd') - mu*rs*B + C  (B=gamma@Wd, C=beta@Wd);
// the residual applies (h-mu)*rs*gamma+beta on the fly. No normalize pass.

typedef __attribute__((ext_vector_type(8))) short bf16x8;
typedef __attribute__((ext_vector_type(4))) float f32x4;

#define PITCH 1032            // ushorts per plane row (1024 + 8 pad, 16B-aligned rows)
#define DPITCH 68             // floats per dbuf row
#define DHALF (16 * DPITCH)   // 1088
#define SMEM_BYTES 75904      // 2*16*1032*2 + 2*1088*4 + 256*4 + 32*4

__device__ __forceinline__ unsigned short f2bf(float f) {
    unsigned u = __float_as_uint(f);
    u = (u + 0x7FFFu + ((u >> 16) & 1u)) >> 16;   // RNE f32 -> bf16
    return (unsigned short)u;
}
__device__ __forceinline__ float bf2f(unsigned short h) {
    return __uint_as_float(((unsigned)h) << 16);
}
__device__ __forceinline__ void split_bf(float f, unsigned short &hi, unsigned short &lo) {
    hi = f2bf(f);
    lo = f2bf(f - bf2f(hi));
}
__device__ __forceinline__ f32x4 MFMA(bf16x8 a, bf16x8 b, f32x4 c) {
    return __builtin_amdgcn_mfma_f32_16x16x32_bf16(a, b, c, 0, 0, 0);
}

// ---------------------------------------------------------------------------
// Pack weights into MFMA fragment order (hi/lo bf16), one 64x64 block per wg.
// blk 0..15 = R[b], 16..31 = L[c], 32..47 = Wd' (gamma-scaled) k-block,
// 48..63 = Wu n-block. blk 64 computes B = gamma@Wd, C = beta@Wd (f32[64] each)
// stored at float offset (64*8192 ushorts).
// Frag addressing (ushorts): blk*8192 + ((kk*4+nt)*2+comp)*512 + lane*8
// element v of lane l:  M[kk*32 + (l>>4)*8 + v][nt*16 + (l&15)]
// ---------------------------------------------------------------------------
__global__ __launch_bounds__(256) void pack_weights(
    const float* __restrict__ R, const float* __restrict__ L,
    const float* __restrict__ Wd, const float* __restrict__ Wu,
    const float* __restrict__ gamma, const float* __restrict__ beta,
    unsigned short* __restrict__ wsp)
{
    const int blk = blockIdx.x;
    const int tid = threadIdx.x;
    if (blk == 64) {                           // B,C reduction block
        __shared__ float red[8][64];
        const int r = tid & 63, part = tid >> 6;       // 4 parts x 64 ranks
        float sb = 0.f, sc = 0.f;
        for (int c = part * 256; c < part * 256 + 256; ++c) {
            const float w = Wd[(size_t)c * 64 + r];
            sb += gamma[c] * w;
            sc += beta[c] * w;
        }
        red[part][r] = sb; red[part + 4][r] = sc;
        __syncthreads();
        if (part == 0) {
            float* bc = (float*)(wsp + (size_t)64 * 8192);
            bc[r]      = red[0][r] + red[1][r] + red[2][r] + red[3][r];
            bc[64 + r] = red[4][r] + red[5][r] + red[6][r] + red[7][r];
        }
        return;
    }
    unsigned short* dst = wsp + (size_t)blk * 8192;
    for (int it = 0; it < 4; ++it) {
        const int slot = tid + it * 256;       // 0..1023
        const int fragidx = slot >> 6;         // 0..15
        const int l = slot & 63;
        const int kk = fragidx >> 3;
        const int nt = (fragidx >> 1) & 3;
        const int comp = fragidx & 1;
        const int g = l >> 4, r16 = l & 15;
        const int j = nt * 16 + r16;
        bf16x8 s;
        #pragma unroll
        for (int v = 0; v < 8; ++v) {
            const int k = kk * 32 + g * 8 + v;
            float w;
            if (blk < 16)      w = R[(size_t)blk * 4096 + k * 64 + j];
            else if (blk < 32) w = L[(size_t)(blk - 16) * 4096 + k * 64 + j];
            else if (blk < 48) {
                const int kglob = (blk - 32) * 64 + k;
                w = gamma[kglob] * Wd[(size_t)kglob * 64 + j];
            } else             w = Wu[(size_t)k * 1024 + (blk - 48) * 64 + j];
            unsigned short hi = f2bf(w);
            unsigned short bits = (comp == 0) ? hi : f2bf(w - bf2f(hi));
            s[v] = (short)bits;
        }
        *(bf16x8*)(dst + fragidx * 512 + l * 8) = s;
    }
}

// ---------------------------------------------------------------------------
// Fused main kernel. 512 threads (8 waves), 16 tokens per workgroup.
// Wave w: grp = w>>2 (splits block/K loops), ntw = w&3 (16-col subtile).
// ---------------------------------------------------------------------------
__global__ __launch_bounds__(512, 4) void qrun_main(
    const float* __restrict__ x, const float* __restrict__ bias,
    const float* __restrict__ gamma, const float* __restrict__ beta,
    const float* __restrict__ thetas, const float* __restrict__ phis,
    const float* __restrict__ Wp, const float* __restrict__ bpv,
    const unsigned short* __restrict__ wpk, float* __restrict__ out)
{
    extern __shared__ char smem[];
    unsigned short* hiP = (unsigned short*)smem;          // [16][PITCH]
    unsigned short* loP = hiP + 16 * PITCH;               // [16][PITCH]
    float* dbuf = (float*)(loP + 16 * PITCH);             // [2][16][DPITCH]
    float* lnpart = dbuf + 2 * DHALF;                     // [8][16][2]
    float* statsR = lnpart + 256;                         // [16][2] (mu, rs)

    const int tid = threadIdx.x;
    const int wave = tid >> 6, lane = tid & 63;
    const int g = lane >> 4, r16 = lane & 15;
    const int grp = wave >> 2, ntw = wave & 3;
    const size_t n0 = (size_t)blockIdx.x * 16;
    const int rowA = r16 * PITCH;

    // ---- phase 0: load x tile, split to hi/lo bf16 planes ----
    {
        #pragma unroll
        for (int it = 0; it < 4; ++it) {
            const int base = (it * 512 + tid) * 8;        // flat element index
            const int row = base >> 10, col = base & 1023;
            const float4 f0 = *(const float4*)(x + n0 * 1024 + base);
            const float4 f1 = *(const float4*)(x + n0 * 1024 + base + 4);
            bf16x8 hv, lv;
            unsigned short hh, ll;
            split_bf(f0.x, hh, ll); hv[0] = (short)hh; lv[0] = (short)ll;
            split_bf(f0.y, hh, ll); hv[1] = (short)hh; lv[1] = (short)ll;
            split_bf(f0.z, hh, ll); hv[2] = (short)hh; lv[2] = (short)ll;
            split_bf(f0.w, hh, ll); hv[3] = (short)hh; lv[3] = (short)ll;
            split_bf(f1.x, hh, ll); hv[4] = (short)hh; lv[4] = (short)ll;
            split_bf(f1.y, hh, ll); hv[5] = (short)hh; lv[5] = (short)ll;
            split_bf(f1.z, hh, ll); hv[6] = (short)hh; lv[6] = (short)ll;
            split_bf(f1.w, hh, ll); hv[7] = (short)hh; lv[7] = (short)ll;
            *(bf16x8*)(hiP + row * PITCH + col) = hv;
            *(bf16x8*)(loP + row * PITCH + col) = lv;
        }
    }
    __syncthreads();

    // ---- phase 1: monarch stage 1 (x @ R[b]); reads all -> barrier -> writes ----
    f32x4 acc1[8];
    #pragma unroll
    for (int bi = 0; bi < 8; ++bi) {
        const int b = grp * 8 + bi;
        const unsigned short* wb = wpk + (size_t)b * 8192;
        bf16x8 Bh0 = *(const bf16x8*)(wb + ((0*4+ntw)*2+0)*512 + lane*8);
        bf16x8 Bl0 = *(const bf16x8*)(wb + ((0*4+ntw)*2+1)*512 + lane*8);
        bf16x8 Bh1 = *(const bf16x8*)(wb + ((1*4+ntw)*2+0)*512 + lane*8);
        bf16x8 Bl1 = *(const bf16x8*)(wb + ((1*4+ntw)*2+1)*512 + lane*8);
        const int ca = b * 64 + g * 8;
        bf16x8 Ah0 = *(const bf16x8*)(hiP + rowA + ca);
        bf16x8 Al0 = *(const bf16x8*)(loP + rowA + ca);
        bf16x8 Ah1 = *(const bf16x8*)(hiP + rowA + ca + 32);
        bf16x8 Al1 = *(const bf16x8*)(loP + rowA + ca + 32);
        f32x4 a = {0.f, 0.f, 0.f, 0.f};
        a = MFMA(Ah0, Bh0, a); a = MFMA(Ah0, Bl0, a); a = MFMA(Al0, Bh0, a);
        a = MFMA(Ah1, Bh1, a); a = MFMA(Ah1, Bl1, a); a = MFMA(Al1, Bh1, a);
        acc1[bi] = a;
    }
    __syncthreads();   // all stage-1 reads complete before permuted overwrite

    // permuted write: value at (row, colD=b*64+ntw*16+r16) -> col
    //   c'=ntw*4+(r16>>2), kk'=(r16>>1)&1, g'=(grp+2*(r16&1)) ^ (r16>>2)  [XOR swizzle]
    //   v'=b&7  -> the 8 blocks are 8 consecutive columns => b128 write.
    {
        const int Cw = (ntw * 4 + (r16 >> 2)) * 64 + ((r16 >> 1) & 1) * 32
                     + (((grp + 2 * (r16 & 1)) ^ (r16 >> 2)) << 3);
        #pragma unroll
        for (int v = 0; v < 4; ++v) {
            const int rowv = (g * 4 + v) * PITCH;
            bf16x8 hv, lv;
            #pragma unroll
            for (int bi = 0; bi < 8; ++bi) {
                unsigned short hh, ll;
                split_bf(acc1[bi][v], hh, ll);
                hv[bi] = (short)hh; lv[bi] = (short)ll;
            }
            *(bf16x8*)(hiP + rowv + Cw) = hv;
            *(bf16x8*)(loP + rowv + Cw) = lv;
        }
    }
    __syncthreads();

    // ---- phase 2: monarch stage 2, operand-swapped: h2^T = L^T @ mid^T ----
    f32x4 acc2[8];
    #pragma unroll
    for (int ci = 0; ci < 8; ++ci) {
        const int c = grp * 8 + ci;
        const unsigned short* wb = wpk + (size_t)(16 + c) * 8192;
        bf16x8 Wh0 = *(const bf16x8*)(wb + ((0*4+ntw)*2+0)*512 + lane*8);
        bf16x8 Wl0 = *(const bf16x8*)(wb + ((0*4+ntw)*2+1)*512 + lane*8);
        bf16x8 Wh1 = *(const bf16x8*)(wb + ((1*4+ntw)*2+0)*512 + lane*8);
        bf16x8 Wl1 = *(const bf16x8*)(wb + ((1*4+ntw)*2+1)*512 + lane*8);
        const int gx = ((g ^ (c & 3)) << 3);               // XOR swizzle (read side)
        const int c0 = rowA + c * 64 + gx;                 // kk=0
        const int c1 = c0 + 32;                            // kk=1
        bf16x8 Hh0 = *(const bf16x8*)(hiP + c0);
        bf16x8 Hl0 = *(const bf16x8*)(loP + c0);
        bf16x8 Hh1 = *(const bf16x8*)(hiP + c1);
        bf16x8 Hl1 = *(const bf16x8*)(loP + c1);
        f32x4 a = {0.f, 0.f, 0.f, 0.f};
        a = MFMA(Wh0, Hh0, a); a = MFMA(Wh0, Hl0, a); a = MFMA(Wl0, Hh0, a);
        a = MFMA(Wh1, Hh1, a); a = MFMA(Wh1, Hl1, a); a = MFMA(Wl1, Hh1, a);
        acc2[ci] = a;
    }
    __syncthreads();   // all permuted-tile reads complete before overwrite

    // epilogue: +bias, write RAW h (hi/lo), LN partial sums
    {
        float s = 0.f, s2 = 0.f;
        #pragma unroll
        for (int ci = 0; ci < 8; ++ci) {
            const int c = grp * 8 + ci;
            const int ncol = c * 64 + ntw * 16 + g * 4;
            const float4 bv = *(const float4*)(bias + ncol);
            float f0 = acc2[ci][0] + bv.x, f1 = acc2[ci][1] + bv.y;
            float f2 = acc2[ci][2] + bv.z, f3 = acc2[ci][3] + bv.w;
            s += f0 + f1 + f2 + f3;
            s2 += f0*f0 + f1*f1 + f2*f2 + f3*f3;
            ushort4 h4, l4;
            split_bf(f0, h4.x, l4.x); split_bf(f1, h4.y, l4.y);
            split_bf(f2, h4.z, l4.z); split_bf(f3, h4.w, l4.w);
            *(ushort4*)(hiP + rowA + ncol) = h4;
            *(ushort4*)(loP + rowA + ncol) = l4;
        }
        s  += __shfl_xor(s, 16);  s  += __shfl_xor(s, 32);
        s2 += __shfl_xor(s2, 16); s2 += __shfl_xor(s2, 32);
        if (g == 0) {
            lnpart[(wave * 16 + r16) * 2]     = s;
            lnpart[(wave * 16 + r16) * 2 + 1] = s2;
        }
    }
    __syncthreads();

    // ---- phase 4: down-proj on RAW h, swapped: draw^T = Wd'^T @ h^T (hi-only) ----
    // 16 spare lanes also reduce LN stats into statsR.
    {
        if (tid < 16) {
            float s = 0.f, s2 = 0.f;
            #pragma unroll
            for (int w = 0; w < 8; ++w) {
                s  += lnpart[(w * 16 + tid) * 2];
                s2 += lnpart[(w * 16 + tid) * 2 + 1];
            }
            const float mu = s * (1.f / 1024.f);
            statsR[tid * 2]     = mu;
            statsR[tid * 2 + 1] = rsqrtf(s2 * (1.f / 1024.f) - mu * mu + 1e-5f);
        }
        f32x4 accd = {0.f, 0.f, 0.f, 0.f};
        #pragma unroll
        for (int ki = 0; ki < 16; ++ki) {
            const int kq = grp * 16 + ki;                 // 32-wide K chunk (of 32)
            const int kb = kq >> 1, kin = kq & 1;
            const unsigned short* wb = wpk + (size_t)(32 + kb) * 8192;
            bf16x8 Wh = *(const bf16x8*)(wb + ((kin*4+ntw)*2+0)*512 + lane*8);
            bf16x8 Hh = *(const bf16x8*)(hiP + rowA + kq * 32 + g * 8);
            accd = MFMA(Wh, Hh, accd);
        }
        // D[rank-local g*4+v][token r16]; rank r = ntw*16 + g*4 + v
        *(f32x4*)(dbuf + grp * DHALF + r16 * DPITCH + ntw * 16 + g * 4) = accd;
    }
    __syncthreads();

    // ---- phase 5: LN-fixup + up-proj + residual + sin/cos + final linear ----
    const float muT = statsR[r16 * 2], rsT = statsR[r16 * 2 + 1];
    float muR[4], rsR[4];
    #pragma unroll
    for (int v = 0; v < 4; ++v) {
        muR[v] = statsR[(g * 4 + v) * 2];
        rsR[v] = statsR[(g * 4 + v) * 2 + 1];
    }
    const float* bc = (const float*)(wpk + (size_t)64 * 8192);
    bf16x8 dA[2];
    #pragma unroll
    for (int kk = 0; kk < 2; ++kk) {
        const int rb = kk * 32 + g * 8;
        const float4 B0 = *(const float4*)(bc + rb);
        const float4 B1 = *(const float4*)(bc + rb + 4);
        const float4 C0 = *(const float4*)(bc + 64 + rb);
        const float4 C1 = *(const float4*)(bc + 64 + rb + 4);
        const int di = r16 * DPITCH + rb;
        const f32x4 q0 = *(const f32x4*)(dbuf + di);
        const f32x4 q1 = *(const f32x4*)(dbuf + di + 4);
        const f32x4 p0 = *(const f32x4*)(dbuf + DHALF + di);
        const f32x4 p1 = *(const f32x4*)(dbuf + DHALF + di + 4);
        const float Ba[8] = {B0.x,B0.y,B0.z,B0.w,B1.x,B1.y,B1.z,B1.w};
        const float Ca[8] = {C0.x,C0.y,C0.z,C0.w,C1.x,C1.y,C1.z,C1.w};
        #pragma unroll
        for (int v = 0; v < 4; ++v) {
            const float d0 = rsT * (q0[v] + p0[v]) - muT * rsT * Ba[v]     + Ca[v];
            const float d1 = rsT * (q1[v] + p1[v]) - muT * rsT * Ba[v + 4] + Ca[v + 4];
            dA[kk][v]     = (short)f2bf(d0);
            dA[kk][v + 4] = (short)f2bf(d1);
        }
    }
    float wp[24];
    #pragma unroll
    for (int k2 = 0; k2 < 24; ++k2) wp[k2] = Wp[k2];
    const float bp0 = bpv[0], bp1 = bpv[1], bp2 = bpv[2], bp3 = bpv[3];
    float gpa[8], bpa[8];
    #pragma unroll
    for (int j = 0; j < 8; ++j) {
        const int p = (wave * 8 + j) * 16 + r16;
        gpa[j] = gamma[p]; bpa[j] = beta[p];
    }

    #pragma unroll 2
    for (int j = 0; j < 8; ++j) {
        const int ntg = wave * 8 + j;
        const int nb = ntg >> 2, ntin = ntg & 3;
        const unsigned short* wb = wpk + (size_t)(48 + nb) * 8192;
        bf16x8 Bh0 = *(const bf16x8*)(wb + ((0*4+ntin)*2+0)*512 + lane*8);
        bf16x8 Bh1 = *(const bf16x8*)(wb + ((1*4+ntin)*2+0)*512 + lane*8);
        f32x4 au = {0.f, 0.f, 0.f, 0.f};
        au = MFMA(dA[0], Bh0, au);
        au = MFMA(dA[1], Bh1, au);
        const int p = ntg * 16 + r16;
        const float th0 = thetas[p], th1 = thetas[1024 + p], th2 = thetas[2048 + p];
        const float ph0 = phis[p],   ph1 = phis[1024 + p],   ph2 = phis[2048 + p];
        #pragma unroll
        for (int v = 0; v < 4; ++v) {
            const int row = g * 4 + v;
            const float hraw = bf2f(hiP[row * PITCH + p]) + bf2f(loP[row * PITCH + p]);
            const float hn = (hraw - muR[v]) * rsR[v] * gpa[j] + bpa[j];
            const float e = au[v] + hn;
            float o0 = bp0, o1 = bp1, o2 = bp2, o3 = bp3;
            {
                const float rot = fmaf(e, th0, ph0);
                const float sn = __sinf(rot), cs = __cosf(rot);
                o0 = fmaf(sn, wp[0],  fmaf(cs, wp[1],  o0));
                o1 = fmaf(sn, wp[6],  fmaf(cs, wp[7],  o1));
                o2 = fmaf(sn, wp[12], fmaf(cs, wp[13], o2));
                o3 = fmaf(sn, wp[18], fmaf(cs, wp[19], o3));
            }
            {
                const float rot = fmaf(e, th1, ph1);
                const float sn = __sinf(rot), cs = __cosf(rot);
                o0 = fmaf(sn, wp[2],  fmaf(cs, wp[3],  o0));
                o1 = fmaf(sn, wp[8],  fmaf(cs, wp[9],  o1));
                o2 = fmaf(sn, wp[14], fmaf(cs, wp[15], o2));
                o3 = fmaf(sn, wp[20], fmaf(cs, wp[21], o3));
            }
            {
                const float rot = fmaf(e, th2, ph2);
                const float sn = __sinf(rot), cs = __cosf(rot);
                o0 = fmaf(sn, wp[4],  fmaf(cs, wp[5],  o0));
                o1 = fmaf(sn, wp[10], fmaf(cs, wp[11], o1));
                o2 = fmaf(sn, wp[16], fmaf(cs, wp[17], o2));
                o3 = fmaf(sn, wp[22], fmaf(cs, wp[23], o3));
            }
            *(float4*)(out + ((n0 + row) * 1024 + p) * 4) = make_float4(o0, o1, o2, o3);
        }
    }
}

extern "C" void kernel_launch(void* const* d_in, const int* in_sizes, int n_in,
                              void* d_out, int out_size, void* d_ws, size_t ws_size,
                              hipStream_t stream) {
    const float* x      = (const float*)d_in[0];
    const float* R      = (const float*)d_in[1];
    const float* L      = (const float*)d_in[2];
    const float* bias   = (const float*)d_in[3];
    const float* gamma  = (const float*)d_in[4];
    const float* beta   = (const float*)d_in[5];
    const float* Wd     = (const float*)d_in[6];
    const float* Wu     = (const float*)d_in[7];
    const float* thetas = (const float*)d_in[8];
    const float* phis   = (const float*)d_in[9];
    const float* Wp     = (const float*)d_in[10];
    const float* bp     = (const float*)d_in[11];
    float* out = (float*)d_out;
    unsigned short* wsp = (unsigned short*)d_ws;
    const int N = in_sizes[0] / 1024;   // 8192 tokens

    (void)hipFuncSetAttribute((const void*)qrun_main,
                              hipFuncAttributeMaxDynamicSharedMemorySize, SMEM_BYTES);
    pack_weights<<<dim3(65), dim3(256), 0, stream>>>(R, L, Wd, Wu, gamma, beta, wsp);
    qrun_main<<<dim3(N / 16), dim3(512), SMEM_BYTES, stream>>>(
        x, bias, gamma, beta, thetas, phis, Wp, bp, wsp, out);
}